// Round 3
// baseline (219.220 us; speedup 1.0000x reference)
//
#include <hip/hip_runtime.h>
#include <math.h>

// ---------------------------------------------------------------------------
// GeoFeatureExtractor: B=256, T=512, N=51 landmarks x 3 (fp32), 114 features.
// Round 3: single fused kernel. Block = 256 threads = 256 consecutive
// timesteps of one batch row. Input staged coalesced into LDS in 3 phases
// (left hand / right hand / face+body) + small wrist/nose halo for temporal
// features. Features in register array F[114], burst-stored as float2.
// LDS layout S[i*63+c]: stride 63 (odd) -> conflict-free both directions.
// ---------------------------------------------------------------------------

#define NF   114
#define NC   153
#define TILE 256
#define HALO 4
#define HN   (TILE + 2 * HALO)   // 264 halo timesteps

struct V3 { float x, y, z; };

__device__ __forceinline__ V3 operator-(V3 a, V3 b) { return {a.x - b.x, a.y - b.y, a.z - b.z}; }
__device__ __forceinline__ V3 operator+(V3 a, V3 b) { return {a.x + b.x, a.y + b.y, a.z + b.z}; }
__device__ __forceinline__ V3 operator*(V3 a, float s) { return {a.x * s, a.y * s, a.z * s}; }
__device__ __forceinline__ float dot3(V3 a, V3 b) { return a.x * b.x + a.y * b.y + a.z * b.z; }
__device__ __forceinline__ V3 cross3(V3 a, V3 b) {
    return {a.y * b.z - a.z * b.y, a.z * b.x - a.x * b.z, a.x * b.y - a.y * b.x};
}
__device__ __forceinline__ float norm3(V3 a) { return sqrtf(dot3(a, a)); }
__device__ __forceinline__ float dist3(V3 a, V3 b) { V3 d = a - b; return sqrtf(dot3(d, d) + 1e-6f); }
__device__ __forceinline__ float acosc(float c) {
    c = fminf(fmaxf(c, -1.0f + 1e-6f), 1.0f - 1e-6f);
    return acosf(c);
}

// boundary-mapped central-diff endpoints (exact _cdiff semantics)
__device__ __forceinline__ void bmap(int tt, int T, int& ta, int& tb) {
    if (tt == 0)          { ta = 0;      tb = 2;     }
    else if (tt == T - 1) { ta = T - 3;  tb = T - 1; }
    else                  { ta = tt - 1; tb = tt + 1; }
}

__global__ __launch_bounds__(256) void geo_fused(
    const float* __restrict__ xyz,
    const float* __restrict__ fmask,
    const float* __restrict__ bmask,
    float* __restrict__ out,
    int T)
{
    __shared__ float S[TILE * 63];   // 64512 B; reused across phases

    const int tid = threadIdx.x;
    const int b   = blockIdx.x >> 1;          // T/TILE == 2 tiles per row
    const int t0  = (blockIdx.x & 1) << 8;
    const int t   = t0 + tid;
    const int bT0 = b * T;
    const int idx = bT0 + t;

    const float fg = fmask[idx];
    const float bg = bmask[idx];

    float F[NF];

    // ======================= Phase 0: halo (wrists + nose) =================
    // S used as H[j*9 + c9], j in [0,HN): timestep t0-4+j (clamped)
    {
        const int offs[9] = {0, 1, 2, 63, 64, 65, 126, 127, 128};
        for (int j = tid; j < HN; j += TILE) {
            int th = t0 - HALO + j;
            th = th < 0 ? 0 : (th > T - 1 ? T - 1 : th);
            const float* rec = xyz + (size_t)(bT0 + th) * NC;
            #pragma unroll
            for (int c9 = 0; c9 < 9; ++c9)
                S[j * 9 + c9] = rec[offs[c9]];
        }
    }
    __syncthreads();

    // ----------------------- temporal features -----------------------------
    {
        auto HP = [&](int cb, int th) -> V3 {
            int j = (th - t0 + HALO) * 9 + cb;
            return V3{S[j], S[j + 1], S[j + 2]};
        };
        auto wvel = [&](int cb, int tt) -> V3 {
            int ta, tb; bmap(tt, T, ta, tb);
            return (HP(cb, tb) - HP(cb, ta)) * 0.5f;
        };
        auto wacc = [&](int cb, int tt) -> V3 {
            int ta, tb; bmap(tt, T, ta, tb);
            return (wvel(cb, tb) - wvel(cb, ta)) * 0.5f;
        };

        V3 velW0 = wvel(0, t), velW1 = wvel(3, t);

        // G: velocity direction (jnp.maximum eps semantics)
        {
            float inv = 1.0f / fmaxf(norm3(velW0), 1e-6f);
            F[80] = velW0.x * inv; F[81] = velW0.y * inv; F[82] = velW0.z * inv;
        }
        {
            float inv = 1.0f / fmaxf(norm3(velW1), 1e-6f);
            F[83] = velW1.x * inv; F[84] = velW1.y * inv; F[85] = velW1.z * inv;
        }
        // H: velocity-turn angle (padded 0 at t = T-1)
        #pragma unroll
        for (int h = 0; h < 2; ++h) {
            float val = 0.0f;
            if (t < T - 1) {
                V3 v0 = (h == 0) ? velW0 : velW1;
                V3 v1 = wvel(h * 3, t + 1);
                V3 a  = v0 * (1.0f / (norm3(v0) + 1e-6f));
                V3 c  = v1 * (1.0f / (norm3(v1) + 1e-6f));
                val = acosc(dot3(a, c));
            }
            F[86 + h] = val;
        }
        // I/J: inter-hand
        V3 p0h = HP(0, t), p21h = HP(3, t);
        F[88] = dist3(p0h, p21h);
        {
            V3 rel = p21h - p0h;
            float inv = 1.0f / (norm3(rel) + 1e-6f);
            F[89] = rel.x * inv; F[90] = rel.y * inv;
        }
        // K: d/dt of dist(wrist, nose)  (plain _norm, no eps)
        #pragma unroll
        for (int h = 0; h < 2; ++h) {
            int ta, tb; bmap(t, T, ta, tb);
            float da = norm3(HP(h * 3, ta) - HP(6, ta));
            float db = norm3(HP(h * 3, tb) - HP(6, tb));
            F[91 + h] = (db - da) * 0.5f;
        }
        // M: hand-velocity alignment
        {
            V3 ldv = velW0 * (1.0f / (norm3(velW0) + 1e-6f));
            V3 rdv = velW1 * (1.0f / (norm3(velW1) + 1e-6f));
            F[97] = dot3(ldv, rdv);
        }
        // N: speed
        F[98] = norm3(velW0);
        F[99] = norm3(velW1);
        // O: accel magnitude
        F[100] = norm3(wacc(0, t));
        F[101] = norm3(wacc(3, t));
        // P: proximity sigmoid
        {
            float hd = norm3(p0h - p21h);
            F[102] = 1.0f / (1.0f + expf(-5.0f * (0.05f - hd)));
        }
    }
    __syncthreads();

    V3 p0, itip0, p21, itip1;   // carried across phases
    constexpr int TRI[15][3] = {
        {0, 1, 2},   {1, 2, 3},   {2, 3, 4},
        {0, 5, 6},   {5, 6, 7},   {6, 7, 8},
        {0, 9, 10},  {9, 10, 11}, {10, 11, 12},
        {0, 13, 14}, {13, 14, 15},{14, 15, 16},
        {0, 17, 18}, {17, 18, 19},{18, 19, 20}};

    // ======================= Phases 1,2: hands =============================
    #pragma unroll
    for (int h = 0; h < 2; ++h) {
        // ---- stage 63 coords x TILE timesteps, coalesced ----
        const int cbase = h * 63;
        #pragma unroll
        for (int k = 0; k < 63; ++k) {
            int p = k * TILE + tid;
            int i = p / 63;
            int c = p - i * 63;
            S[i * 63 + c] = xyz[(size_t)(bT0 + t0 + i) * NC + cbase + c];
        }
        __syncthreads();

        const float* R = S + tid * 63;   // this thread's 21 landmarks
        auto PL = [&](int lm) -> V3 {
            int c = 3 * lm;
            return V3{R[c], R[c + 1], R[c + 2]};
        };

        // Block A: tips + curls + cross + d_ti
        {
            V3 t_tip = PL(4),  i_tip = PL(8),  m_tip = PL(12);
            V3 r_tip = PL(16), p_tip = PL(20);
            int oa = h * 12;
            F[oa + 0] = dist3(t_tip, i_tip);
            F[oa + 1] = dist3(i_tip, m_tip);
            F[oa + 2] = dist3(m_tip, r_tip);
            F[oa + 3] = dist3(r_tip, p_tip);
            F[oa + 4] = dist3(t_tip, p_tip);
            V3 tm = PL(2),  tj = PL(3);
            F[oa + 5] = dist3(tm, t_tip) / (dist3(tm, tj) + 1e-4f);
            V3 im = PL(5),  ij = PL(6);
            F[oa + 6] = dist3(im, i_tip) / (dist3(im, ij) + 1e-4f);
            V3 mm = PL(9),  mj = PL(10);
            F[oa + 7] = dist3(mm, m_tip) / (dist3(mm, mj) + 1e-4f);
            V3 rm = PL(13), rj = PL(14);
            F[oa + 8] = dist3(rm, r_tip) / (dist3(rm, rj) + 1e-4f);
            V3 pm = PL(17), pj = PL(18);
            F[oa + 9] = dist3(pm, p_tip) / (dist3(pm, pj) + 1e-4f);
            F[oa + 10] = i_tip.x - m_tip.x;
            F[oa + 11] = dist3(t_tip, im);
            // Block L: tip x-diffs
            F[93 + 2 * h + 0] = i_tip.x - m_tip.x;
            F[93 + 2 * h + 1] = m_tip.x - r_tip.x;
            // carry index tip
            if (h == 0) itip0 = i_tip; else itip1 = i_tip;
        }
        // Block C: joint angles
        #pragma unroll
        for (int i = 0; i < 15; ++i) {
            V3 pj = PL(TRI[i][1]);
            V3 v1 = PL(TRI[i][0]) - pj;
            V3 v2 = PL(TRI[i][2]) - pj;
            F[34 + h * 15 + i] = acosc(dot3(v1, v2) / (norm3(v1) * norm3(v2) + 1e-6f));
        }
        // Blocks D/F: palm normal + n.up / n.fwd
        {
            V3 w = PL(0);
            V3 n = cross3(PL(5) - w, PL(17) - w);
            float inv = 1.0f / (norm3(n) + 1e-6f);
            n = n * inv;
            F[64 + 3 * h + 0] = n.x;
            F[64 + 3 * h + 1] = n.y;
            F[64 + 3 * h + 2] = n.z;
            F[76 + 2 * h + 0] = n.y;
            F[76 + 2 * h + 1] = n.z;
            // Block E: spread angles
            V3 v5  = PL(5)  - w;
            V3 v9  = PL(9)  - w;
            V3 v13 = PL(13) - w;
            V3 v17 = PL(17) - w;
            F[70 + 3 * h + 0] = acosc(dot3(v5,  v9)  / (norm3(v5)  * norm3(v9)  + 1e-6f));
            F[70 + 3 * h + 1] = acosc(dot3(v9,  v13) / (norm3(v9)  * norm3(v13) + 1e-6f));
            F[70 + 3 * h + 2] = acosc(dot3(v13, v17) / (norm3(v13) * norm3(v17) + 1e-6f));
            // carry wrist
            if (h == 0) p0 = w; else p21 = w;
        }
        __syncthreads();   // before LDS reuse by next phase
    }

    // ======================= Phase 3: face + body ==========================
    #pragma unroll
    for (int k = 0; k < 27; ++k) {
        int p = k * TILE + tid;
        int i = p / 27;
        int c = p - i * 27;
        S[i * 27 + c] = xyz[(size_t)(bT0 + t0 + i) * NC + 126 + c];
    }
    __syncthreads();
    {
        const float* R = S + tid * 27;
        auto FL = [&](int k) -> V3 {
            int c = 3 * k;
            return V3{R[c], R[c + 1], R[c + 2]};
        };
        V3 nose = FL(0), chin = FL(1), fore = FL(2);
        // Block B: face distances * fg
        F[24] = dist3(p0,  nose) * fg;
        F[25] = dist3(p0,  chin) * fg;
        F[26] = dist3(p0,  fore) * fg;
        F[27] = dist3(p21, nose) * fg;
        F[28] = dist3(p21, chin) * fg;
        F[29] = dist3(p21, fore) * fg;
        F[30] = dist3(itip0, nose) * fg;
        F[31] = dist3(itip0, fore) * fg;
        F[32] = dist3(itip1, nose) * fg;
        F[33] = dist3(itip1, fore) * fg;
        // Block Q: body features * bg
        V3 lsh = FL(3), rsh = FL(4);
        V3 shmid = (lsh + rsh) * 0.5f;
        float shw = dist3(lsh, rsh);
        float invw = 1.0f / (shw + 1e-6f);
        F[103] = (p0.y  - shmid.y) * invw * bg;
        F[104] = (p0.x  - shmid.x) * invw * bg;
        F[105] = dist3(p0, lsh) * bg;
        F[106] = dist3(p0, FL(5)) * bg;
        F[107] = (p21.y - shmid.y) * invw * bg;
        F[108] = (p21.x - shmid.x) * invw * bg;
        F[109] = dist3(p21, rsh) * bg;
        F[110] = dist3(p21, FL(6)) * bg;
        F[111] = shw * bg;
        V3 mouth = (FL(7) + FL(8)) * 0.5f;
        F[112] = dist3(p0,  mouth) * bg;
        F[113] = dist3(p21, mouth) * bg;
    }

    // ======================= burst store (float2, rows 8B-aligned) =========
    float* o = out + (size_t)idx * NF;
    #pragma unroll
    for (int f = 0; f < NF; f += 2) {
        float2 v; v.x = F[f]; v.y = F[f + 1];
        *reinterpret_cast<float2*>(o + f) = v;
    }
}

// ---------------------------------------------------------------------------
// Fallback: direct kernel (correct for any shape; used if tiling assumptions
// don't hold)
// ---------------------------------------------------------------------------
__constant__ int c_TRI[15][3] = {
    {0, 1, 2},   {1, 2, 3},   {2, 3, 4},
    {0, 5, 6},   {5, 6, 7},   {6, 7, 8},
    {0, 9, 10},  {9, 10, 11}, {10, 11, 12},
    {0, 13, 14}, {13, 14, 15},{14, 15, 16},
    {0, 17, 18}, {17, 18, 19},{18, 19, 20}};

__global__ __launch_bounds__(256) void geo_direct(
    const float* __restrict__ xyz,
    const float* __restrict__ fmask,
    const float* __restrict__ bmask,
    float* __restrict__ out,
    int BT, int T)
{
    int idx = blockIdx.x * blockDim.x + threadIdx.x;
    if (idx >= BT) return;
    int b = idx / T;
    int t = idx - b * T;
    int bT0 = b * T;

    auto ldp = [&](int tt, int lm) -> V3 {
        const float* p = xyz + ((size_t)(bT0 + tt) * 51 + (size_t)lm) * 3;
        return V3{p[0], p[1], p[2]};
    };
    auto P = [&](int lm) -> V3 { return ldp(t, lm); };
    auto velAt = [&](int lm, int tt) -> V3 {
        int ta, tb; bmap(tt, T, ta, tb);
        return (ldp(tb, lm) - ldp(ta, lm)) * 0.5f;
    };
    auto accAt = [&](int lm, int tt) -> V3 {
        int ta, tb; bmap(tt, T, ta, tb);
        return (velAt(lm, tb) - velAt(lm, ta)) * 0.5f;
    };

    float fg = fmask[idx];
    float bg = bmask[idx];
    float* o = out + (size_t)idx * NF;

    for (int h = 0; h < 2; ++h) {
        int base = h * 21;
        V3 t_tip = P(base + 4),  i_tip = P(base + 8),  m_tip = P(base + 12);
        V3 r_tip = P(base + 16), p_tip = P(base + 20);
        float* oa = o + h * 12;
        oa[0] = dist3(t_tip, i_tip);
        oa[1] = dist3(i_tip, m_tip);
        oa[2] = dist3(m_tip, r_tip);
        oa[3] = dist3(r_tip, p_tip);
        oa[4] = dist3(t_tip, p_tip);
        V3 tm = P(base + 2),  tj = P(base + 3);
        oa[5] = dist3(tm, t_tip) / (dist3(tm, tj) + 1e-4f);
        V3 im = P(base + 5),  ij = P(base + 6);
        oa[6] = dist3(im, i_tip) / (dist3(im, ij) + 1e-4f);
        V3 mm = P(base + 9),  mj = P(base + 10);
        oa[7] = dist3(mm, m_tip) / (dist3(mm, mj) + 1e-4f);
        V3 rm = P(base + 13), rj = P(base + 14);
        oa[8] = dist3(rm, r_tip) / (dist3(rm, rj) + 1e-4f);
        V3 pm = P(base + 17), pj = P(base + 18);
        oa[9] = dist3(pm, p_tip) / (dist3(pm, pj) + 1e-4f);
        oa[10] = i_tip.x - m_tip.x;
        oa[11] = dist3(t_tip, im);
    }

    V3 p0 = P(0), p21 = P(21);
    V3 nose = P(42), chin = P(43), fore = P(44);
    V3 itip0 = P(8), itip1 = P(29);
    o[24] = dist3(p0, nose) * fg;
    o[25] = dist3(p0, chin) * fg;
    o[26] = dist3(p0, fore) * fg;
    o[27] = dist3(p21, nose) * fg;
    o[28] = dist3(p21, chin) * fg;
    o[29] = dist3(p21, fore) * fg;
    o[30] = dist3(itip0, nose) * fg;
    o[31] = dist3(itip0, fore) * fg;
    o[32] = dist3(itip1, nose) * fg;
    o[33] = dist3(itip1, fore) * fg;

    for (int h = 0; h < 2; ++h) {
        int base = h * 21;
        for (int i = 0; i < 15; ++i) {
            V3 pj = P(base + c_TRI[i][1]);
            V3 v1 = P(base + c_TRI[i][0]) - pj;
            V3 v2 = P(base + c_TRI[i][2]) - pj;
            o[34 + h * 15 + i] = acosc(dot3(v1, v2) / (norm3(v1) * norm3(v2) + 1e-6f));
        }
    }

    V3 nrm[2];
    for (int h = 0; h < 2; ++h) {
        int base = h * 21;
        V3 w = (h == 0) ? p0 : p21;
        V3 n = cross3(P(base + 5) - w, P(base + 17) - w);
        float inv = 1.0f / (norm3(n) + 1e-6f);
        n = n * inv;
        nrm[h] = n;
        o[64 + 3 * h + 0] = n.x;
        o[64 + 3 * h + 1] = n.y;
        o[64 + 3 * h + 2] = n.z;
    }

    for (int h = 0; h < 2; ++h) {
        int base = h * 21;
        V3 w = (h == 0) ? p0 : p21;
        V3 v5  = P(base + 5)  - w;
        V3 v9  = P(base + 9)  - w;
        V3 v13 = P(base + 13) - w;
        V3 v17 = P(base + 17) - w;
        o[70 + 3 * h + 0] = acosc(dot3(v5,  v9)  / (norm3(v5)  * norm3(v9)  + 1e-6f));
        o[70 + 3 * h + 1] = acosc(dot3(v9,  v13) / (norm3(v9)  * norm3(v13) + 1e-6f));
        o[70 + 3 * h + 2] = acosc(dot3(v13, v17) / (norm3(v13) * norm3(v17) + 1e-6f));
    }

    for (int h = 0; h < 2; ++h) {
        o[76 + 2 * h + 0] = nrm[h].y;
        o[76 + 2 * h + 1] = nrm[h].z;
    }

    V3 velW[2];
    for (int h = 0; h < 2; ++h) {
        V3 v = velAt(h * 21, t);
        velW[h] = v;
        float inv = 1.0f / fmaxf(norm3(v), 1e-6f);
        o[80 + 3 * h + 0] = v.x * inv;
        o[80 + 3 * h + 1] = v.y * inv;
        o[80 + 3 * h + 2] = v.z * inv;
    }

    for (int h = 0; h < 2; ++h) {
        float val = 0.0f;
        if (t < T - 1) {
            V3 v0 = velW[h];
            V3 v1 = velAt(h * 21, t + 1);
            V3 a = v0 * (1.0f / (norm3(v0) + 1e-6f));
            V3 c = v1 * (1.0f / (norm3(v1) + 1e-6f));
            val = acosc(dot3(a, c));
        }
        o[86 + h] = val;
    }

    o[88] = dist3(p0, p21);
    {
        V3 rel = p21 - p0;
        float inv = 1.0f / (norm3(rel) + 1e-6f);
        o[89] = rel.x * inv;
        o[90] = rel.y * inv;
    }

    for (int h = 0; h < 2; ++h) {
        int lm = h * 21;
        int ta, tb; bmap(t, T, ta, tb);
        float da = norm3(ldp(ta, lm) - ldp(ta, 42));
        float db = norm3(ldp(tb, lm) - ldp(tb, 42));
        o[91 + h] = (db - da) * 0.5f;
    }

    for (int h = 0; h < 2; ++h) {
        int base = h * 21;
        float ix = P(base + 8).x, mx = P(base + 12).x, rx = P(base + 16).x;
        o[93 + 2 * h + 0] = ix - mx;
        o[93 + 2 * h + 1] = mx - rx;
    }

    {
        V3 ldv = velW[0] * (1.0f / (norm3(velW[0]) + 1e-6f));
        V3 rdv = velW[1] * (1.0f / (norm3(velW[1]) + 1e-6f));
        o[97] = dot3(ldv, rdv);
    }

    o[98] = norm3(velW[0]);
    o[99] = norm3(velW[1]);
    o[100] = norm3(accAt(0, t));
    o[101] = norm3(accAt(21, t));

    {
        float hd = norm3(p0 - p21);
        o[102] = 1.0f / (1.0f + expf(-5.0f * (0.05f - hd)));
    }

    {
        V3 lsh = P(45), rsh = P(46);
        V3 shmid = (lsh + rsh) * 0.5f;
        float shw = dist3(lsh, rsh);
        float invw = 1.0f / (shw + 1e-6f);
        o[103] = (p0.y - shmid.y) * invw * bg;
        o[104] = (p0.x - shmid.x) * invw * bg;
        o[105] = dist3(p0, lsh) * bg;
        o[106] = dist3(p0, P(47)) * bg;
        o[107] = (p21.y - shmid.y) * invw * bg;
        o[108] = (p21.x - shmid.x) * invw * bg;
        o[109] = dist3(p21, rsh) * bg;
        o[110] = dist3(p21, P(48)) * bg;
        o[111] = shw * bg;
        V3 mouth = (P(49) + P(50)) * 0.5f;
        o[112] = dist3(p0, mouth) * bg;
        o[113] = dist3(p21, mouth) * bg;
    }
}

extern "C" void kernel_launch(void* const* d_in, const int* in_sizes, int n_in,
                              void* d_out, int out_size, void* d_ws, size_t ws_size,
                              hipStream_t stream) {
    const float* xyz   = (const float*)d_in[0];
    const float* fmask = (const float*)d_in[1];
    const float* bmask = (const float*)d_in[2];
    float* out = (float*)d_out;

    const int BT = in_sizes[1];   // B*T (face_mask element count)
    const int T  = 512;           // per reference setup_inputs

    if (T == 2 * TILE && BT % T == 0) {
        // 512 blocks = exactly 2 per CU (LDS-bound occupancy), one full pass
        geo_fused<<<BT / TILE, TILE, 0, stream>>>(xyz, fmask, bmask, out, T);
    } else {
        const int threads = 256;
        geo_direct<<<(BT + threads - 1) / threads, threads, 0, stream>>>(
            xyz, fmask, bmask, out, BT, T);
    }
}

// Round 4
// 164.791 us; speedup vs baseline: 1.3303x; 1.3303x over previous
//
#include <hip/hip_runtime.h>
#include <math.h>

// ---------------------------------------------------------------------------
// GeoFeatureExtractor: B=256, T=512, N=51 landmarks x 3 (fp32), 114 features.
// Round 4: latency-bound fix. One WAVE per block (TILE=64 timesteps), LDS cut
// to 19.2 KB -> 8 independent waves/CU, no block-wide barrier coupling.
// Staging uses pad-to-64 trick: iter k loads record k's 64 consecutive floats
// with lane = coordinate (coalesced, zero index math). LDS strides 65/33/9
// (odd / odd / odd-ish) -> <=2-way bank aliasing = free on CDNA4.
// Features in register array F[114], burst-stored as float2.
// ---------------------------------------------------------------------------

#define NF   114
#define NC   153
#define TILE 64
#define HSTR 65                 // hand buffer stride (floats)
#define FSTR 33                 // face buffer stride (floats)
#define HALO 4
#define HN   (TILE + 2 * HALO)  // 72 halo timesteps

struct V3 { float x, y, z; };

__device__ __forceinline__ V3 operator-(V3 a, V3 b) { return {a.x - b.x, a.y - b.y, a.z - b.z}; }
__device__ __forceinline__ V3 operator+(V3 a, V3 b) { return {a.x + b.x, a.y + b.y, a.z + b.z}; }
__device__ __forceinline__ V3 operator*(V3 a, float s) { return {a.x * s, a.y * s, a.z * s}; }
__device__ __forceinline__ float dot3(V3 a, V3 b) { return a.x * b.x + a.y * b.y + a.z * b.z; }
__device__ __forceinline__ V3 cross3(V3 a, V3 b) {
    return {a.y * b.z - a.z * b.y, a.z * b.x - a.x * b.z, a.x * b.y - a.y * b.x};
}
__device__ __forceinline__ float norm3(V3 a) { return sqrtf(dot3(a, a)); }
__device__ __forceinline__ float dist3(V3 a, V3 b) { V3 d = a - b; return sqrtf(dot3(d, d) + 1e-6f); }
__device__ __forceinline__ float acosc(float c) {
    c = fminf(fmaxf(c, -1.0f + 1e-6f), 1.0f - 1e-6f);
    return acosf(c);
}

// boundary-mapped central-diff endpoints (exact _cdiff semantics)
__device__ __forceinline__ void bmap(int tt, int T, int& ta, int& tb) {
    if (tt == 0)          { ta = 0;      tb = 2;     }
    else if (tt == T - 1) { ta = T - 3;  tb = T - 1; }
    else                  { ta = tt - 1; tb = tt + 1; }
}

__global__ __launch_bounds__(64, 2) void geo_fused(
    const float* __restrict__ xyz,
    const float* __restrict__ fmask,
    const float* __restrict__ bmask,
    float* __restrict__ out,
    int T)
{
    __shared__ float Sh[TILE * HSTR];   // 16640 B, reused: hand0 -> hand1 -> face
    __shared__ float Hb[HN * 9];        // 2592 B, wrist/nose halo

    const int tid = threadIdx.x;                 // 0..63 (one wave)
    const int tilesPerRow = T / TILE;
    const int b   = blockIdx.x / tilesPerRow;
    const int t0  = (blockIdx.x - b * tilesPerRow) * TILE;
    const int t   = t0 + tid;
    const int bT0 = b * T;
    const int idx = bT0 + t;

    const float fg = fmask[idx];
    const float bg = bmask[idx];

    float F[NF];

    // ===== issue halo loads (own buffer) — in flight alongside hand0 =======
    {
        const int offs[9] = {0, 1, 2, 63, 64, 65, 126, 127, 128};
        #pragma unroll
        for (int rr = 0; rr < 2; ++rr) {
            int j = tid + (rr << 6);
            if (j < HN) {
                int th = t0 - HALO + j;
                th = th < 0 ? 0 : (th > T - 1 ? T - 1 : th);
                const float* rec = xyz + (size_t)(bT0 + th) * NC;
                #pragma unroll
                for (int c = 0; c < 9; ++c)
                    Hb[j * 9 + c] = rec[offs[c]];
            }
        }
    }

    // ===== stage hand 0: iter k = record k, lane = coordinate (pad to 64) ==
    {
        const float* gb = xyz + (size_t)(bT0 + t0) * NC;   // hand0 at coord 0
        #pragma unroll
        for (int k = 0; k < TILE; ++k)
            Sh[k * HSTR + tid] = gb[(size_t)k * NC + tid]; // tid=63 -> junk (in-bounds)
    }
    __syncthreads();   // single wave: compiles to waitcnt (cheap)

    // ===== temporal features from halo ======================================
    {
        auto HP = [&](int cb, int th) -> V3 {
            int j = (th - t0 + HALO) * 9 + cb;
            return V3{Hb[j], Hb[j + 1], Hb[j + 2]};
        };
        auto wvel = [&](int cb, int tt) -> V3 {
            int ta, tb; bmap(tt, T, ta, tb);
            return (HP(cb, tb) - HP(cb, ta)) * 0.5f;
        };
        auto wacc = [&](int cb, int tt) -> V3 {
            int ta, tb; bmap(tt, T, ta, tb);
            return (wvel(cb, tb) - wvel(cb, ta)) * 0.5f;
        };

        V3 velW0 = wvel(0, t), velW1 = wvel(3, t);

        { // G: velocity direction (jnp.maximum eps)
            float inv = 1.0f / fmaxf(norm3(velW0), 1e-6f);
            F[80] = velW0.x * inv; F[81] = velW0.y * inv; F[82] = velW0.z * inv;
        }
        {
            float inv = 1.0f / fmaxf(norm3(velW1), 1e-6f);
            F[83] = velW1.x * inv; F[84] = velW1.y * inv; F[85] = velW1.z * inv;
        }
        // H: velocity-turn angle (padded 0 at t = T-1)
        #pragma unroll
        for (int h = 0; h < 2; ++h) {
            float val = 0.0f;
            if (t < T - 1) {
                V3 v0 = (h == 0) ? velW0 : velW1;
                V3 v1 = wvel(h * 3, t + 1);
                V3 a  = v0 * (1.0f / (norm3(v0) + 1e-6f));
                V3 c  = v1 * (1.0f / (norm3(v1) + 1e-6f));
                val = acosc(dot3(a, c));
            }
            F[86 + h] = val;
        }
        // I/J: inter-hand
        V3 p0h = HP(0, t), p21h = HP(3, t);
        F[88] = dist3(p0h, p21h);
        {
            V3 rel = p21h - p0h;
            float inv = 1.0f / (norm3(rel) + 1e-6f);
            F[89] = rel.x * inv; F[90] = rel.y * inv;
        }
        // K: d/dt of dist(wrist, nose)  (plain _norm, no eps)
        #pragma unroll
        for (int h = 0; h < 2; ++h) {
            int ta, tb; bmap(t, T, ta, tb);
            float da = norm3(HP(h * 3, ta) - HP(6, ta));
            float db = norm3(HP(h * 3, tb) - HP(6, tb));
            F[91 + h] = (db - da) * 0.5f;
        }
        // M: hand-velocity alignment
        {
            V3 ldv = velW0 * (1.0f / (norm3(velW0) + 1e-6f));
            V3 rdv = velW1 * (1.0f / (norm3(velW1) + 1e-6f));
            F[97] = dot3(ldv, rdv);
        }
        // N: speed
        F[98] = norm3(velW0);
        F[99] = norm3(velW1);
        // O: accel magnitude
        F[100] = norm3(wacc(0, t));
        F[101] = norm3(wacc(3, t));
        // P: proximity sigmoid
        {
            float hd = norm3(p0h - p21h);
            F[102] = 1.0f / (1.0f + expf(-5.0f * (0.05f - hd)));
        }
    }

    V3 p0, p21, itip0, itip1;   // carried across phases
    constexpr int TRI[15][3] = {
        {0, 1, 2},   {1, 2, 3},   {2, 3, 4},
        {0, 5, 6},   {5, 6, 7},   {6, 7, 8},
        {0, 9, 10},  {9, 10, 11}, {10, 11, 12},
        {0, 13, 14}, {13, 14, 15},{14, 15, 16},
        {0, 17, 18}, {17, 18, 19},{18, 19, 20}};

    // ===== per-hand features (hand0 staged; hand1 staged after) ============
    #pragma unroll
    for (int h = 0; h < 2; ++h) {
        if (h == 1) {
            __syncthreads();   // hand0 reads done before overwrite
            const float* gb = xyz + (size_t)(bT0 + t0) * NC + 63;
            #pragma unroll
            for (int k = 0; k < TILE; ++k)
                Sh[k * HSTR + tid] = gb[(size_t)k * NC + tid]; // tid=63 -> coord126 (junk, in-bounds)
            __syncthreads();
        }

        const float* R = Sh + tid * HSTR;   // this thread's 21 landmarks
        auto PL = [&](int lm) -> V3 {
            int c = 3 * lm;
            return V3{R[c], R[c + 1], R[c + 2]};
        };

        // Block A: tips + curls + cross + d_ti
        {
            V3 t_tip = PL(4),  i_tip = PL(8),  m_tip = PL(12);
            V3 r_tip = PL(16), p_tip = PL(20);
            int oa = h * 12;
            F[oa + 0] = dist3(t_tip, i_tip);
            F[oa + 1] = dist3(i_tip, m_tip);
            F[oa + 2] = dist3(m_tip, r_tip);
            F[oa + 3] = dist3(r_tip, p_tip);
            F[oa + 4] = dist3(t_tip, p_tip);
            V3 tm = PL(2),  tj = PL(3);
            F[oa + 5] = dist3(tm, t_tip) / (dist3(tm, tj) + 1e-4f);
            V3 im = PL(5),  ij = PL(6);
            F[oa + 6] = dist3(im, i_tip) / (dist3(im, ij) + 1e-4f);
            V3 mm = PL(9),  mj = PL(10);
            F[oa + 7] = dist3(mm, m_tip) / (dist3(mm, mj) + 1e-4f);
            V3 rm = PL(13), rj = PL(14);
            F[oa + 8] = dist3(rm, r_tip) / (dist3(rm, rj) + 1e-4f);
            V3 pm = PL(17), pj = PL(18);
            F[oa + 9] = dist3(pm, p_tip) / (dist3(pm, pj) + 1e-4f);
            F[oa + 10] = i_tip.x - m_tip.x;
            F[oa + 11] = dist3(t_tip, im);
            // Block L: tip x-diffs
            F[93 + 2 * h + 0] = i_tip.x - m_tip.x;
            F[93 + 2 * h + 1] = m_tip.x - r_tip.x;
            if (h == 0) itip0 = i_tip; else itip1 = i_tip;
        }
        // Block C: joint angles
        #pragma unroll
        for (int i = 0; i < 15; ++i) {
            V3 pj = PL(TRI[i][1]);
            V3 v1 = PL(TRI[i][0]) - pj;
            V3 v2 = PL(TRI[i][2]) - pj;
            F[34 + h * 15 + i] = acosc(dot3(v1, v2) / (norm3(v1) * norm3(v2) + 1e-6f));
        }
        // Blocks D/F: palm normal + n.up / n.fwd ; Block E: spread angles
        {
            V3 w = PL(0);
            V3 n = cross3(PL(5) - w, PL(17) - w);
            float inv = 1.0f / (norm3(n) + 1e-6f);
            n = n * inv;
            F[64 + 3 * h + 0] = n.x;
            F[64 + 3 * h + 1] = n.y;
            F[64 + 3 * h + 2] = n.z;
            F[76 + 2 * h + 0] = n.y;
            F[76 + 2 * h + 1] = n.z;
            V3 v5  = PL(5)  - w;
            V3 v9  = PL(9)  - w;
            V3 v13 = PL(13) - w;
            V3 v17 = PL(17) - w;
            F[70 + 3 * h + 0] = acosc(dot3(v5,  v9)  / (norm3(v5)  * norm3(v9)  + 1e-6f));
            F[70 + 3 * h + 1] = acosc(dot3(v9,  v13) / (norm3(v9)  * norm3(v13) + 1e-6f));
            F[70 + 3 * h + 2] = acosc(dot3(v13, v17) / (norm3(v13) * norm3(v17) + 1e-6f));
            if (h == 0) p0 = w; else p21 = w;
        }
    }

    // ===== face + body: coords 121..152 (5 junk + 27 real), coalesced ======
    __syncthreads();
    {
        const float* gf = xyz + (size_t)(bT0 + t0) * NC + 121;
        #pragma unroll
        for (int k = 0; k < 32; ++k) {
            int rec = 2 * k + (tid >> 5);
            int c   = tid & 31;
            Sh[rec * FSTR + c] = gf[(size_t)rec * NC + c];
        }
    }
    __syncthreads();
    {
        const float* R2 = Sh + tid * FSTR;
        auto FL = [&](int k) -> V3 {   // k = landmark - 42
            int c = 5 + 3 * k;         // coord 126+3k -> buffer col (126+3k)-121
            return V3{R2[c], R2[c + 1], R2[c + 2]};
        };
        V3 nose = FL(0), chin = FL(1), fore = FL(2);
        // Block B: face distances * fg
        F[24] = dist3(p0,  nose) * fg;
        F[25] = dist3(p0,  chin) * fg;
        F[26] = dist3(p0,  fore) * fg;
        F[27] = dist3(p21, nose) * fg;
        F[28] = dist3(p21, chin) * fg;
        F[29] = dist3(p21, fore) * fg;
        F[30] = dist3(itip0, nose) * fg;
        F[31] = dist3(itip0, fore) * fg;
        F[32] = dist3(itip1, nose) * fg;
        F[33] = dist3(itip1, fore) * fg;
        // Block Q: body features * bg
        V3 lsh = FL(3), rsh = FL(4);
        V3 shmid = (lsh + rsh) * 0.5f;
        float shw = dist3(lsh, rsh);
        float invw = 1.0f / (shw + 1e-6f);
        F[103] = (p0.y  - shmid.y) * invw * bg;
        F[104] = (p0.x  - shmid.x) * invw * bg;
        F[105] = dist3(p0, lsh) * bg;
        F[106] = dist3(p0, FL(5)) * bg;
        F[107] = (p21.y - shmid.y) * invw * bg;
        F[108] = (p21.x - shmid.x) * invw * bg;
        F[109] = dist3(p21, rsh) * bg;
        F[110] = dist3(p21, FL(6)) * bg;
        F[111] = shw * bg;
        V3 mouth = (FL(7) + FL(8)) * 0.5f;
        F[112] = dist3(p0,  mouth) * bg;
        F[113] = dist3(p21, mouth) * bg;
    }

    // ===== burst store (float2; rows 456 B -> 8 B aligned) =================
    float* o = out + (size_t)idx * NF;
    #pragma unroll
    for (int f = 0; f < NF; f += 2) {
        float2 v; v.x = F[f]; v.y = F[f + 1];
        *reinterpret_cast<float2*>(o + f) = v;
    }
}

// ---------------------------------------------------------------------------
// Fallback: direct kernel (correct for any shape)
// ---------------------------------------------------------------------------
__constant__ int c_TRI[15][3] = {
    {0, 1, 2},   {1, 2, 3},   {2, 3, 4},
    {0, 5, 6},   {5, 6, 7},   {6, 7, 8},
    {0, 9, 10},  {9, 10, 11}, {10, 11, 12},
    {0, 13, 14}, {13, 14, 15},{14, 15, 16},
    {0, 17, 18}, {17, 18, 19},{18, 19, 20}};

__global__ __launch_bounds__(256) void geo_direct(
    const float* __restrict__ xyz,
    const float* __restrict__ fmask,
    const float* __restrict__ bmask,
    float* __restrict__ out,
    int BT, int T)
{
    int idx = blockIdx.x * blockDim.x + threadIdx.x;
    if (idx >= BT) return;
    int b = idx / T;
    int t = idx - b * T;
    int bT0 = b * T;

    auto ldp = [&](int tt, int lm) -> V3 {
        const float* p = xyz + ((size_t)(bT0 + tt) * 51 + (size_t)lm) * 3;
        return V3{p[0], p[1], p[2]};
    };
    auto P = [&](int lm) -> V3 { return ldp(t, lm); };
    auto velAt = [&](int lm, int tt) -> V3 {
        int ta, tb; bmap(tt, T, ta, tb);
        return (ldp(tb, lm) - ldp(ta, lm)) * 0.5f;
    };
    auto accAt = [&](int lm, int tt) -> V3 {
        int ta, tb; bmap(tt, T, ta, tb);
        return (velAt(lm, tb) - velAt(lm, ta)) * 0.5f;
    };

    float fg = fmask[idx];
    float bg = bmask[idx];
    float* o = out + (size_t)idx * NF;

    for (int h = 0; h < 2; ++h) {
        int base = h * 21;
        V3 t_tip = P(base + 4),  i_tip = P(base + 8),  m_tip = P(base + 12);
        V3 r_tip = P(base + 16), p_tip = P(base + 20);
        float* oa = o + h * 12;
        oa[0] = dist3(t_tip, i_tip);
        oa[1] = dist3(i_tip, m_tip);
        oa[2] = dist3(m_tip, r_tip);
        oa[3] = dist3(r_tip, p_tip);
        oa[4] = dist3(t_tip, p_tip);
        V3 tm = P(base + 2),  tj = P(base + 3);
        oa[5] = dist3(tm, t_tip) / (dist3(tm, tj) + 1e-4f);
        V3 im = P(base + 5),  ij = P(base + 6);
        oa[6] = dist3(im, i_tip) / (dist3(im, ij) + 1e-4f);
        V3 mm = P(base + 9),  mj = P(base + 10);
        oa[7] = dist3(mm, m_tip) / (dist3(mm, mj) + 1e-4f);
        V3 rm = P(base + 13), rj = P(base + 14);
        oa[8] = dist3(rm, r_tip) / (dist3(rm, rj) + 1e-4f);
        V3 pm = P(base + 17), pj = P(base + 18);
        oa[9] = dist3(pm, p_tip) / (dist3(pm, pj) + 1e-4f);
        oa[10] = i_tip.x - m_tip.x;
        oa[11] = dist3(t_tip, im);
    }

    V3 p0 = P(0), p21 = P(21);
    V3 nose = P(42), chin = P(43), fore = P(44);
    V3 itip0 = P(8), itip1 = P(29);
    o[24] = dist3(p0, nose) * fg;
    o[25] = dist3(p0, chin) * fg;
    o[26] = dist3(p0, fore) * fg;
    o[27] = dist3(p21, nose) * fg;
    o[28] = dist3(p21, chin) * fg;
    o[29] = dist3(p21, fore) * fg;
    o[30] = dist3(itip0, nose) * fg;
    o[31] = dist3(itip0, fore) * fg;
    o[32] = dist3(itip1, nose) * fg;
    o[33] = dist3(itip1, fore) * fg;

    for (int h = 0; h < 2; ++h) {
        int base = h * 21;
        for (int i = 0; i < 15; ++i) {
            V3 pj = P(base + c_TRI[i][1]);
            V3 v1 = P(base + c_TRI[i][0]) - pj;
            V3 v2 = P(base + c_TRI[i][2]) - pj;
            o[34 + h * 15 + i] = acosc(dot3(v1, v2) / (norm3(v1) * norm3(v2) + 1e-6f));
        }
    }

    V3 nrm[2];
    for (int h = 0; h < 2; ++h) {
        int base = h * 21;
        V3 w = (h == 0) ? p0 : p21;
        V3 n = cross3(P(base + 5) - w, P(base + 17) - w);
        float inv = 1.0f / (norm3(n) + 1e-6f);
        n = n * inv;
        nrm[h] = n;
        o[64 + 3 * h + 0] = n.x;
        o[64 + 3 * h + 1] = n.y;
        o[64 + 3 * h + 2] = n.z;
    }

    for (int h = 0; h < 2; ++h) {
        int base = h * 21;
        V3 w = (h == 0) ? p0 : p21;
        V3 v5  = P(base + 5)  - w;
        V3 v9  = P(base + 9)  - w;
        V3 v13 = P(base + 13) - w;
        V3 v17 = P(base + 17) - w;
        o[70 + 3 * h + 0] = acosc(dot3(v5,  v9)  / (norm3(v5)  * norm3(v9)  + 1e-6f));
        o[70 + 3 * h + 1] = acosc(dot3(v9,  v13) / (norm3(v9)  * norm3(v13) + 1e-6f));
        o[70 + 3 * h + 2] = acosc(dot3(v13, v17) / (norm3(v13) * norm3(v17) + 1e-6f));
    }

    for (int h = 0; h < 2; ++h) {
        o[76 + 2 * h + 0] = nrm[h].y;
        o[76 + 2 * h + 1] = nrm[h].z;
    }

    V3 velW[2];
    for (int h = 0; h < 2; ++h) {
        V3 v = velAt(h * 21, t);
        velW[h] = v;
        float inv = 1.0f / fmaxf(norm3(v), 1e-6f);
        o[80 + 3 * h + 0] = v.x * inv;
        o[80 + 3 * h + 1] = v.y * inv;
        o[80 + 3 * h + 2] = v.z * inv;
    }

    for (int h = 0; h < 2; ++h) {
        float val = 0.0f;
        if (t < T - 1) {
            V3 v0 = velW[h];
            V3 v1 = velAt(h * 21, t + 1);
            V3 a = v0 * (1.0f / (norm3(v0) + 1e-6f));
            V3 c = v1 * (1.0f / (norm3(v1) + 1e-6f));
            val = acosc(dot3(a, c));
        }
        o[86 + h] = val;
    }

    o[88] = dist3(p0, p21);
    {
        V3 rel = p21 - p0;
        float inv = 1.0f / (norm3(rel) + 1e-6f);
        o[89] = rel.x * inv;
        o[90] = rel.y * inv;
    }

    for (int h = 0; h < 2; ++h) {
        int lm = h * 21;
        int ta, tb; bmap(t, T, ta, tb);
        float da = norm3(ldp(ta, lm) - ldp(ta, 42));
        float db = norm3(ldp(tb, lm) - ldp(tb, 42));
        o[91 + h] = (db - da) * 0.5f;
    }

    for (int h = 0; h < 2; ++h) {
        int base = h * 21;
        float ix = P(base + 8).x, mx = P(base + 12).x, rx = P(base + 16).x;
        o[93 + 2 * h + 0] = ix - mx;
        o[93 + 2 * h + 1] = mx - rx;
    }

    {
        V3 ldv = velW[0] * (1.0f / (norm3(velW[0]) + 1e-6f));
        V3 rdv = velW[1] * (1.0f / (norm3(velW[1]) + 1e-6f));
        o[97] = dot3(ldv, rdv);
    }

    o[98] = norm3(velW[0]);
    o[99] = norm3(velW[1]);
    o[100] = norm3(accAt(0, t));
    o[101] = norm3(accAt(21, t));

    {
        float hd = norm3(p0 - p21);
        o[102] = 1.0f / (1.0f + expf(-5.0f * (0.05f - hd)));
    }

    {
        V3 lsh = P(45), rsh = P(46);
        V3 shmid = (lsh + rsh) * 0.5f;
        float shw = dist3(lsh, rsh);
        float invw = 1.0f / (shw + 1e-6f);
        o[103] = (p0.y - shmid.y) * invw * bg;
        o[104] = (p0.x - shmid.x) * invw * bg;
        o[105] = dist3(p0, lsh) * bg;
        o[106] = dist3(p0, P(47)) * bg;
        o[107] = (p21.y - shmid.y) * invw * bg;
        o[108] = (p21.x - shmid.x) * invw * bg;
        o[109] = dist3(p21, rsh) * bg;
        o[110] = dist3(p21, P(48)) * bg;
        o[111] = shw * bg;
        V3 mouth = (P(49) + P(50)) * 0.5f;
        o[112] = dist3(p0, mouth) * bg;
        o[113] = dist3(p21, mouth) * bg;
    }
}

extern "C" void kernel_launch(void* const* d_in, const int* in_sizes, int n_in,
                              void* d_out, int out_size, void* d_ws, size_t ws_size,
                              hipStream_t stream) {
    const float* xyz   = (const float*)d_in[0];
    const float* fmask = (const float*)d_in[1];
    const float* bmask = (const float*)d_in[2];
    float* out = (float*)d_out;

    const int BT = in_sizes[1];   // B*T (face_mask element count)
    const int T  = 512;           // per reference setup_inputs

    if (T % TILE == 0 && BT % T == 0 && T >= 3 * TILE) {
        // 2048 one-wave blocks, 8 independent waves/CU (LDS 19.2 KB/block)
        geo_fused<<<BT / TILE, TILE, 0, stream>>>(xyz, fmask, bmask, out, T);
    } else {
        const int threads = 256;
        geo_direct<<<(BT + threads - 1) / threads, threads, 0, stream>>>(
            xyz, fmask, bmask, out, BT, T);
    }
}

// Round 5
// 162.333 us; speedup vs baseline: 1.3504x; 1.0151x over previous
//
#include <hip/hip_runtime.h>
#include <math.h>

// ---------------------------------------------------------------------------
// GeoFeatureExtractor: B=256, T=512, N=51 landmarks x 3 (fp32), 114 features.
// Round 5: kill the exposed latency. One wave per block (64 timesteps).
// ALL staging issued up front via __builtin_amdgcn_global_load_lds (async
// global->LDS DMA, no VGPR round-trip, cannot be compiler-sunk):
//   Sh0 <- hand0 (64 DMA), Sh1 <- hand1 (64 DMA), Hb <- halo (VGPR loads),
//   one barrier, then compute phases run stall-free. Face DMA reuses Sh0 and
//   streams behind hand1 compute. LDS 36 KB -> 4 blocks/CU (occupancy traded
//   for zero-stall pipelining; grid caps occupancy at 8/CU anyway).
// VALU cut: Hastings acos (err ~7e-5), __expf, v_rcp/v_sqrt intrinsics.
// ---------------------------------------------------------------------------

#define NF   114
#define NC   153
#define TILE 64
#define HSTR 65                 // hand buffer stride (65 = odd -> conflict-free)
#define FSTR 33                 // face buffer stride (odd)
#define HALO 4
#define HN   (TILE + 2 * HALO)  // 72 halo timesteps

#if defined(__has_builtin)
#if __has_builtin(__builtin_amdgcn_global_load_lds)
#define USE_DMA 1
#endif
#endif
#ifndef USE_DMA
#define USE_DMA 0
#endif

typedef const __attribute__((address_space(1))) void gas_t;
typedef __attribute__((address_space(3))) void las_t;

// per-lane global addr g; LDS dest = uniform base `lds` + lane*4 (exec-masked)
__device__ __forceinline__ void dma4(const float* g, float* lds) {
#if USE_DMA
    __builtin_amdgcn_global_load_lds((gas_t*)g, (las_t*)lds, 4, 0, 0);
#else
    lds[threadIdx.x & 63] = *g;
#endif
}

struct V3 { float x, y, z; };

__device__ __forceinline__ V3 operator-(V3 a, V3 b) { return {a.x - b.x, a.y - b.y, a.z - b.z}; }
__device__ __forceinline__ V3 operator+(V3 a, V3 b) { return {a.x + b.x, a.y + b.y, a.z + b.z}; }
__device__ __forceinline__ V3 operator*(V3 a, float s) { return {a.x * s, a.y * s, a.z * s}; }
__device__ __forceinline__ float dot3(V3 a, V3 b) { return a.x * b.x + a.y * b.y + a.z * b.z; }
__device__ __forceinline__ V3 cross3(V3 a, V3 b) {
    return {a.y * b.z - a.z * b.y, a.z * b.x - a.x * b.z, a.x * b.y - a.y * b.x};
}

__device__ __forceinline__ float fsqrt(float x) { return __builtin_amdgcn_sqrtf(x); }
__device__ __forceinline__ float frcp(float x)  { return __builtin_amdgcn_rcpf(x); }

__device__ __forceinline__ float norm3(V3 a) { return fsqrt(dot3(a, a)); }
__device__ __forceinline__ float dist3(V3 a, V3 b) { V3 d = a - b; return fsqrt(dot3(d, d) + 1e-6f); }

// clip + Hastings acos approximation, |err| < 7e-5 rad (threshold is 2.45)
__device__ __forceinline__ float acosc(float c) {
    c = fminf(fmaxf(c, -1.0f + 1e-6f), 1.0f - 1e-6f);
    float ax = fabsf(c);
    float r = fsqrt(1.0f - ax) *
              (1.5707288f + ax * (-0.2121144f + ax * (0.0742610f - 0.0187293f * ax)));
    return c < 0.0f ? 3.14159265358979f - r : r;
}

// boundary-mapped central-diff endpoints (exact _cdiff semantics)
__device__ __forceinline__ void bmap(int tt, int T, int& ta, int& tb) {
    if (tt == 0)          { ta = 0;      tb = 2;     }
    else if (tt == T - 1) { ta = T - 3;  tb = T - 1; }
    else                  { ta = tt - 1; tb = tt + 1; }
}

__global__ __launch_bounds__(64, 2) void geo_fused(
    const float* __restrict__ xyz,
    const float* __restrict__ fmask,
    const float* __restrict__ bmask,
    float* __restrict__ out,
    int T)
{
    __shared__ float Sh0[TILE * HSTR];   // 16640 B: hand0, then reused for face
    __shared__ float Sh1[TILE * HSTR];   // 16640 B: hand1
    __shared__ float Hb[HN * 9];         // 2592 B: wrist/nose halo

    const int tid = threadIdx.x;                 // 0..63 (one wave)
    const int tilesPerRow = T / TILE;
    const int b   = blockIdx.x / tilesPerRow;
    const int t0  = (blockIdx.x - b * tilesPerRow) * TILE;
    const int t   = t0 + tid;
    const int bT0 = b * T;
    const int idx = bT0 + t;

    const float* gb = xyz + (size_t)(bT0 + t0) * NC;

    // ===== issue ALL bulk staging up front (fire-and-forget DMA) ===========
    #pragma unroll
    for (int k = 0; k < TILE; ++k)                    // hand0: coords 0..63
        dma4(gb + (size_t)k * NC + tid, Sh0 + k * HSTR);
    #pragma unroll
    for (int k = 0; k < TILE; ++k)                    // hand1: coords 63..126
        dma4(gb + (size_t)k * NC + 63 + tid, Sh1 + k * HSTR);

    // halo (small, scattered): normal loads + ds_write
    {
        const int offs[9] = {0, 1, 2, 63, 64, 65, 126, 127, 128};
        #pragma unroll
        for (int rr = 0; rr < 2; ++rr) {
            int j = tid + (rr << 6);
            if (j < HN) {
                int th = t0 - HALO + j;
                th = th < 0 ? 0 : (th > T - 1 ? T - 1 : th);
                const float* rec = xyz + (size_t)(bT0 + th) * NC;
                #pragma unroll
                for (int c = 0; c < 9; ++c)
                    Hb[j * 9 + c] = rec[offs[c]];
            }
        }
    }

    const float fg = fmask[idx];
    const float bg = bmask[idx];

    __syncthreads();   // drains DMA (vmcnt) + halo ds_writes (lgkm); 1 wave -> cheap

    float F[NF];

    // ===== temporal features from halo =====================================
    {
        auto HP = [&](int cb, int th) -> V3 {
            int j = (th - t0 + HALO) * 9 + cb;
            return V3{Hb[j], Hb[j + 1], Hb[j + 2]};
        };
        auto wvel = [&](int cb, int tt) -> V3 {
            int ta, tb; bmap(tt, T, ta, tb);
            return (HP(cb, tb) - HP(cb, ta)) * 0.5f;
        };
        auto wacc = [&](int cb, int tt) -> V3 {
            int ta, tb; bmap(tt, T, ta, tb);
            return (wvel(cb, tb) - wvel(cb, ta)) * 0.5f;
        };

        V3 velW0 = wvel(0, t), velW1 = wvel(3, t);

        { // G: velocity direction (jnp.maximum eps)
            float inv = frcp(fmaxf(norm3(velW0), 1e-6f));
            F[80] = velW0.x * inv; F[81] = velW0.y * inv; F[82] = velW0.z * inv;
        }
        {
            float inv = frcp(fmaxf(norm3(velW1), 1e-6f));
            F[83] = velW1.x * inv; F[84] = velW1.y * inv; F[85] = velW1.z * inv;
        }
        // H: velocity-turn angle (padded 0 at t = T-1)
        #pragma unroll
        for (int h = 0; h < 2; ++h) {
            float val = 0.0f;
            if (t < T - 1) {
                V3 v0 = (h == 0) ? velW0 : velW1;
                V3 v1 = wvel(h * 3, t + 1);
                V3 a  = v0 * frcp(norm3(v0) + 1e-6f);
                V3 c  = v1 * frcp(norm3(v1) + 1e-6f);
                val = acosc(dot3(a, c));
            }
            F[86 + h] = val;
        }
        // I/J: inter-hand
        V3 p0h = HP(0, t), p21h = HP(3, t);
        F[88] = dist3(p0h, p21h);
        {
            V3 rel = p21h - p0h;
            float inv = frcp(norm3(rel) + 1e-6f);
            F[89] = rel.x * inv; F[90] = rel.y * inv;
        }
        // K: d/dt of dist(wrist, nose)  (plain _norm, no eps)
        #pragma unroll
        for (int h = 0; h < 2; ++h) {
            int ta, tb; bmap(t, T, ta, tb);
            float da = norm3(HP(h * 3, ta) - HP(6, ta));
            float db = norm3(HP(h * 3, tb) - HP(6, tb));
            F[91 + h] = (db - da) * 0.5f;
        }
        // M: hand-velocity alignment
        {
            V3 ldv = velW0 * frcp(norm3(velW0) + 1e-6f);
            V3 rdv = velW1 * frcp(norm3(velW1) + 1e-6f);
            F[97] = dot3(ldv, rdv);
        }
        // N: speed
        F[98] = norm3(velW0);
        F[99] = norm3(velW1);
        // O: accel magnitude
        F[100] = norm3(wacc(0, t));
        F[101] = norm3(wacc(3, t));
        // P: proximity sigmoid
        {
            float hd = norm3(p0h - p21h);
            F[102] = frcp(1.0f + __expf(-5.0f * (0.05f - hd)));
        }
    }

    V3 p0, p21, itip0, itip1;

    // ===== per-hand features (Sh0 then Sh1; all data already resident) =====
    auto handFeats = [&](const float* R, int h, V3& wrist, V3& itip) {
        constexpr int TRI[15][3] = {
            {0, 1, 2},   {1, 2, 3},   {2, 3, 4},
            {0, 5, 6},   {5, 6, 7},   {6, 7, 8},
            {0, 9, 10},  {9, 10, 11}, {10, 11, 12},
            {0, 13, 14}, {13, 14, 15},{14, 15, 16},
            {0, 17, 18}, {17, 18, 19},{18, 19, 20}};
        auto PL = [&](int lm) -> V3 {
            int c = 3 * lm;
            return V3{R[c], R[c + 1], R[c + 2]};
        };
        // Block A: tips + curls + cross + d_ti
        V3 t_tip = PL(4),  i_tip = PL(8),  m_tip = PL(12);
        V3 r_tip = PL(16), p_tip = PL(20);
        int oa = h * 12;
        F[oa + 0] = dist3(t_tip, i_tip);
        F[oa + 1] = dist3(i_tip, m_tip);
        F[oa + 2] = dist3(m_tip, r_tip);
        F[oa + 3] = dist3(r_tip, p_tip);
        F[oa + 4] = dist3(t_tip, p_tip);
        V3 tm = PL(2),  tj = PL(3);
        F[oa + 5] = dist3(tm, t_tip) * frcp(dist3(tm, tj) + 1e-4f);
        V3 im = PL(5),  ij = PL(6);
        F[oa + 6] = dist3(im, i_tip) * frcp(dist3(im, ij) + 1e-4f);
        V3 mm = PL(9),  mj = PL(10);
        F[oa + 7] = dist3(mm, m_tip) * frcp(dist3(mm, mj) + 1e-4f);
        V3 rm = PL(13), rj = PL(14);
        F[oa + 8] = dist3(rm, r_tip) * frcp(dist3(rm, rj) + 1e-4f);
        V3 pm = PL(17), pj = PL(18);
        F[oa + 9] = dist3(pm, p_tip) * frcp(dist3(pm, pj) + 1e-4f);
        F[oa + 10] = i_tip.x - m_tip.x;
        F[oa + 11] = dist3(t_tip, im);
        // Block L: tip x-diffs
        F[93 + 2 * h + 0] = i_tip.x - m_tip.x;
        F[93 + 2 * h + 1] = m_tip.x - r_tip.x;
        itip = i_tip;
        // Block C: joint angles
        #pragma unroll
        for (int i = 0; i < 15; ++i) {
            V3 pjv = PL(TRI[i][1]);
            V3 v1 = PL(TRI[i][0]) - pjv;
            V3 v2 = PL(TRI[i][2]) - pjv;
            F[34 + h * 15 + i] = acosc(dot3(v1, v2) * frcp(norm3(v1) * norm3(v2) + 1e-6f));
        }
        // Blocks D/F: palm normal + n.up / n.fwd ; Block E: spread angles
        V3 w = PL(0);
        V3 n = cross3(PL(5) - w, PL(17) - w);
        float inv = frcp(norm3(n) + 1e-6f);
        n = n * inv;
        F[64 + 3 * h + 0] = n.x;
        F[64 + 3 * h + 1] = n.y;
        F[64 + 3 * h + 2] = n.z;
        F[76 + 2 * h + 0] = n.y;
        F[76 + 2 * h + 1] = n.z;
        V3 v5  = PL(5)  - w;
        V3 v9  = PL(9)  - w;
        V3 v13 = PL(13) - w;
        V3 v17 = PL(17) - w;
        F[70 + 3 * h + 0] = acosc(dot3(v5,  v9)  * frcp(norm3(v5)  * norm3(v9)  + 1e-6f));
        F[70 + 3 * h + 1] = acosc(dot3(v9,  v13) * frcp(norm3(v9)  * norm3(v13) + 1e-6f));
        F[70 + 3 * h + 2] = acosc(dot3(v13, v17) * frcp(norm3(v13) * norm3(v17) + 1e-6f));
        wrist = w;
    };

    handFeats(Sh0 + tid * HSTR, 0, p0, itip0);

    // Sh0 reads done -> barrier, then face DMA streams behind hand1 compute
    __syncthreads();
    {
        const float* gf = gb + 121;            // coords 121..152 (incl. face/body)
        float* Sf = Sh0;                       // reuse, rows of 33 floats
        if (tid < 32) {
            #pragma unroll
            for (int k = 0; k < TILE; ++k)     // exec-masked 32-lane DMA per record
                dma4(gf + (size_t)k * NC + tid, Sf + k * FSTR);
        }
    }

    handFeats(Sh1 + tid * HSTR, 1, p21, itip1);

    __syncthreads();   // drains face DMA

    // ===== face + body =====================================================
    {
        const float* R2 = Sh0 + tid * FSTR;
        auto FL = [&](int k) -> V3 {           // k = landmark - 42
            int c = 5 + 3 * k;                 // coord 126+3k at buffer col (126+3k)-121
            return V3{R2[c], R2[c + 1], R2[c + 2]};
        };
        V3 nose = FL(0), chin = FL(1), fore = FL(2);
        // Block B: face distances * fg
        F[24] = dist3(p0,  nose) * fg;
        F[25] = dist3(p0,  chin) * fg;
        F[26] = dist3(p0,  fore) * fg;
        F[27] = dist3(p21, nose) * fg;
        F[28] = dist3(p21, chin) * fg;
        F[29] = dist3(p21, fore) * fg;
        F[30] = dist3(itip0, nose) * fg;
        F[31] = dist3(itip0, fore) * fg;
        F[32] = dist3(itip1, nose) * fg;
        F[33] = dist3(itip1, fore) * fg;
        // Block Q: body features * bg
        V3 lsh = FL(3), rsh = FL(4);
        V3 shmid = (lsh + rsh) * 0.5f;
        float shw = dist3(lsh, rsh);
        float invw = frcp(shw + 1e-6f);
        F[103] = (p0.y  - shmid.y) * invw * bg;
        F[104] = (p0.x  - shmid.x) * invw * bg;
        F[105] = dist3(p0, lsh) * bg;
        F[106] = dist3(p0, FL(5)) * bg;
        F[107] = (p21.y - shmid.y) * invw * bg;
        F[108] = (p21.x - shmid.x) * invw * bg;
        F[109] = dist3(p21, rsh) * bg;
        F[110] = dist3(p21, FL(6)) * bg;
        F[111] = shw * bg;
        V3 mouth = (FL(7) + FL(8)) * 0.5f;
        F[112] = dist3(p0,  mouth) * bg;
        F[113] = dist3(p21, mouth) * bg;
    }

    // ===== burst store (float2; rows 456 B -> 8 B aligned) =================
    float* o = out + (size_t)idx * NF;
    #pragma unroll
    for (int f = 0; f < NF; f += 2) {
        float2 v; v.x = F[f]; v.y = F[f + 1];
        *reinterpret_cast<float2*>(o + f) = v;
    }
}

// ---------------------------------------------------------------------------
// Fallback: direct kernel (correct for any shape)
// ---------------------------------------------------------------------------
__constant__ int c_TRI[15][3] = {
    {0, 1, 2},   {1, 2, 3},   {2, 3, 4},
    {0, 5, 6},   {5, 6, 7},   {6, 7, 8},
    {0, 9, 10},  {9, 10, 11}, {10, 11, 12},
    {0, 13, 14}, {13, 14, 15},{14, 15, 16},
    {0, 17, 18}, {17, 18, 19},{18, 19, 20}};

__global__ __launch_bounds__(256) void geo_direct(
    const float* __restrict__ xyz,
    const float* __restrict__ fmask,
    const float* __restrict__ bmask,
    float* __restrict__ out,
    int BT, int T)
{
    int idx = blockIdx.x * blockDim.x + threadIdx.x;
    if (idx >= BT) return;
    int b = idx / T;
    int t = idx - b * T;
    int bT0 = b * T;

    auto ldp = [&](int tt, int lm) -> V3 {
        const float* p = xyz + ((size_t)(bT0 + tt) * 51 + (size_t)lm) * 3;
        return V3{p[0], p[1], p[2]};
    };
    auto P = [&](int lm) -> V3 { return ldp(t, lm); };
    auto velAt = [&](int lm, int tt) -> V3 {
        int ta, tb; bmap(tt, T, ta, tb);
        return (ldp(tb, lm) - ldp(ta, lm)) * 0.5f;
    };
    auto accAt = [&](int lm, int tt) -> V3 {
        int ta, tb; bmap(tt, T, ta, tb);
        return (velAt(lm, tb) - velAt(lm, ta)) * 0.5f;
    };

    float fg = fmask[idx];
    float bg = bmask[idx];
    float* o = out + (size_t)idx * NF;

    for (int h = 0; h < 2; ++h) {
        int base = h * 21;
        V3 t_tip = P(base + 4),  i_tip = P(base + 8),  m_tip = P(base + 12);
        V3 r_tip = P(base + 16), p_tip = P(base + 20);
        float* oa = o + h * 12;
        oa[0] = dist3(t_tip, i_tip);
        oa[1] = dist3(i_tip, m_tip);
        oa[2] = dist3(m_tip, r_tip);
        oa[3] = dist3(r_tip, p_tip);
        oa[4] = dist3(t_tip, p_tip);
        V3 tm = P(base + 2),  tj = P(base + 3);
        oa[5] = dist3(tm, t_tip) / (dist3(tm, tj) + 1e-4f);
        V3 im = P(base + 5),  ij = P(base + 6);
        oa[6] = dist3(im, i_tip) / (dist3(im, ij) + 1e-4f);
        V3 mm = P(base + 9),  mj = P(base + 10);
        oa[7] = dist3(mm, m_tip) / (dist3(mm, mj) + 1e-4f);
        V3 rm = P(base + 13), rj = P(base + 14);
        oa[8] = dist3(rm, r_tip) / (dist3(rm, rj) + 1e-4f);
        V3 pm = P(base + 17), pj = P(base + 18);
        oa[9] = dist3(pm, p_tip) / (dist3(pm, pj) + 1e-4f);
        oa[10] = i_tip.x - m_tip.x;
        oa[11] = dist3(t_tip, im);
    }

    V3 p0 = P(0), p21 = P(21);
    V3 nose = P(42), chin = P(43), fore = P(44);
    V3 itip0 = P(8), itip1 = P(29);
    o[24] = dist3(p0, nose) * fg;
    o[25] = dist3(p0, chin) * fg;
    o[26] = dist3(p0, fore) * fg;
    o[27] = dist3(p21, nose) * fg;
    o[28] = dist3(p21, chin) * fg;
    o[29] = dist3(p21, fore) * fg;
    o[30] = dist3(itip0, nose) * fg;
    o[31] = dist3(itip0, fore) * fg;
    o[32] = dist3(itip1, nose) * fg;
    o[33] = dist3(itip1, fore) * fg;

    for (int h = 0; h < 2; ++h) {
        int base = h * 21;
        for (int i = 0; i < 15; ++i) {
            V3 pj = P(base + c_TRI[i][1]);
            V3 v1 = P(base + c_TRI[i][0]) - pj;
            V3 v2 = P(base + c_TRI[i][2]) - pj;
            o[34 + h * 15 + i] = acosc(dot3(v1, v2) / (norm3(v1) * norm3(v2) + 1e-6f));
        }
    }

    V3 nrm[2];
    for (int h = 0; h < 2; ++h) {
        int base = h * 21;
        V3 w = (h == 0) ? p0 : p21;
        V3 n = cross3(P(base + 5) - w, P(base + 17) - w);
        float inv = 1.0f / (norm3(n) + 1e-6f);
        n = n * inv;
        nrm[h] = n;
        o[64 + 3 * h + 0] = n.x;
        o[64 + 3 * h + 1] = n.y;
        o[64 + 3 * h + 2] = n.z;
    }

    for (int h = 0; h < 2; ++h) {
        int base = h * 21;
        V3 w = (h == 0) ? p0 : p21;
        V3 v5  = P(base + 5)  - w;
        V3 v9  = P(base + 9)  - w;
        V3 v13 = P(base + 13) - w;
        V3 v17 = P(base + 17) - w;
        o[70 + 3 * h + 0] = acosc(dot3(v5,  v9)  / (norm3(v5)  * norm3(v9)  + 1e-6f));
        o[70 + 3 * h + 1] = acosc(dot3(v9,  v13) / (norm3(v9)  * norm3(v13) + 1e-6f));
        o[70 + 3 * h + 2] = acosc(dot3(v13, v17) / (norm3(v13) * norm3(v17) + 1e-6f));
    }

    for (int h = 0; h < 2; ++h) {
        o[76 + 2 * h + 0] = nrm[h].y;
        o[76 + 2 * h + 1] = nrm[h].z;
    }

    V3 velW[2];
    for (int h = 0; h < 2; ++h) {
        V3 v = velAt(h * 21, t);
        velW[h] = v;
        float inv = 1.0f / fmaxf(norm3(v), 1e-6f);
        o[80 + 3 * h + 0] = v.x * inv;
        o[80 + 3 * h + 1] = v.y * inv;
        o[80 + 3 * h + 2] = v.z * inv;
    }

    for (int h = 0; h < 2; ++h) {
        float val = 0.0f;
        if (t < T - 1) {
            V3 v0 = velW[h];
            V3 v1 = velAt(h * 21, t + 1);
            V3 a = v0 * (1.0f / (norm3(v0) + 1e-6f));
            V3 c = v1 * (1.0f / (norm3(v1) + 1e-6f));
            val = acosc(dot3(a, c));
        }
        o[86 + h] = val;
    }

    o[88] = dist3(p0, p21);
    {
        V3 rel = p21 - p0;
        float inv = 1.0f / (norm3(rel) + 1e-6f);
        o[89] = rel.x * inv;
        o[90] = rel.y * inv;
    }

    for (int h = 0; h < 2; ++h) {
        int lm = h * 21;
        int ta, tb; bmap(t, T, ta, tb);
        float da = norm3(ldp(ta, lm) - ldp(ta, 42));
        float db = norm3(ldp(tb, lm) - ldp(tb, 42));
        o[91 + h] = (db - da) * 0.5f;
    }

    for (int h = 0; h < 2; ++h) {
        int base = h * 21;
        float ix = P(base + 8).x, mx = P(base + 12).x, rx = P(base + 16).x;
        o[93 + 2 * h + 0] = ix - mx;
        o[93 + 2 * h + 1] = mx - rx;
    }

    {
        V3 ldv = velW[0] * (1.0f / (norm3(velW[0]) + 1e-6f));
        V3 rdv = velW[1] * (1.0f / (norm3(velW[1]) + 1e-6f));
        o[97] = dot3(ldv, rdv);
    }

    o[98] = norm3(velW[0]);
    o[99] = norm3(velW[1]);
    o[100] = norm3(accAt(0, t));
    o[101] = norm3(accAt(21, t));

    {
        float hd = norm3(p0 - p21);
        o[102] = 1.0f / (1.0f + expf(-5.0f * (0.05f - hd)));
    }

    {
        V3 lsh = P(45), rsh = P(46);
        V3 shmid = (lsh + rsh) * 0.5f;
        float shw = dist3(lsh, rsh);
        float invw = 1.0f / (shw + 1e-6f);
        o[103] = (p0.y - shmid.y) * invw * bg;
        o[104] = (p0.x - shmid.x) * invw * bg;
        o[105] = dist3(p0, lsh) * bg;
        o[106] = dist3(p0, P(47)) * bg;
        o[107] = (p21.y - shmid.y) * invw * bg;
        o[108] = (p21.x - shmid.x) * invw * bg;
        o[109] = dist3(p21, rsh) * bg;
        o[110] = dist3(p21, P(48)) * bg;
        o[111] = shw * bg;
        V3 mouth = (P(49) + P(50)) * 0.5f;
        o[112] = dist3(p0, mouth) * bg;
        o[113] = dist3(p21, mouth) * bg;
    }
}

extern "C" void kernel_launch(void* const* d_in, const int* in_sizes, int n_in,
                              void* d_out, int out_size, void* d_ws, size_t ws_size,
                              hipStream_t stream) {
    const float* xyz   = (const float*)d_in[0];
    const float* fmask = (const float*)d_in[1];
    const float* bmask = (const float*)d_in[2];
    float* out = (float*)d_out;

    const int BT = in_sizes[1];   // B*T (face_mask element count)
    const int T  = 512;           // per reference setup_inputs

    if (T % TILE == 0 && BT % T == 0 && T >= 3 * TILE) {
        // 2048 one-wave blocks; LDS 36 KB -> 4 resident/CU, zero-stall pipeline
        geo_fused<<<BT / TILE, TILE, 0, stream>>>(xyz, fmask, bmask, out, T);
    } else {
        const int threads = 256;
        geo_direct<<<(BT + threads - 1) / threads, threads, 0, stream>>>(
            xyz, fmask, bmask, out, BT, T);
    }
}